// Round 10
// baseline (84.379 us; speedup 1.0000x reference)
//
#include <hip/hip_runtime.h>

// QuantumAttention: B=8, S=2048, E=8, H=2, D=4, NQ=8
//
// Ledger (rocprof-anchored): total = fill 40.5 + 17.5 fixed harness/graph
// + attn + merge 2.6. R14 (pk-packed fp32, M=2) = 83.8 best; attn ~23us,
// now LDS-broadcast-pipe bound (4096 bcast ds_read_b128/CU x ~12cyc = 20.5).
// Dead broadcast mechanisms: readlane (SGPR hazard, 63us), DPP rotate
// (serial dep, 39us), vector-uniform global load (R8, no scalarization,
// ~36us), cross-block fusion (89us). R15: SMEM broadcast -- prep kernel
// materializes K/V to ws; attn reads them via ADDRSPACE(4) pointer with
// readfirstlane-uniformed wave base -> compiler emits s_load_dwordx8 (one
// scalar op per j, K$-cached, separate pipe). Inner loop: zero LDS, zero
// VMEM; 9 pk-VALU + 2 exp per j, SGPR splats feed VOP3P directly.
// K/V fma chain in prep identical to old LDS staging -> bits unchanged.
//
// Quantum circuit closed-form: c_w = cos(tok[w]+tok[w%4]);
// z[0]=c1..c7, z[q>=1]=c0..cq. Softmax one-pass (scores bounded, fp32 safe);
// 0.5*log2(e) folded into Wq so inner exp is bare v_exp_f32 (exp2).

#define SS 2048
#define EE 8

typedef float v2f __attribute__((ext_vector_type(2)));
typedef __attribute__((address_space(4))) const float c4f;   // s_load path

// ---- prep: K,V for all (b,h,j): kvws[((b*2+h)*SS + j)*2 + {0,1}] ----
extern "C" __global__ __launch_bounds__(128)
void qa_prep15(const float* __restrict__ x, const float* __restrict__ Wk,
               const float* __restrict__ Wv, float4* __restrict__ kvws) {
    __shared__ float wrow[128];   // [0:64) Wk, [64:128) Wv
    const int tid = threadIdx.x;
    wrow[tid] = (tid < 64) ? Wk[tid] : Wv[tid - 64];
    __syncthreads();

    const int g = blockIdx.x * 128 + tid;   // token 0..16383
    const int b = g >> 11, s = g & 2047;
    const float* xp = x + (size_t)g * EE;
    float xv[8];
    *(float4*)&xv[0] = *(const float4*)xp;
    *(float4*)&xv[4] = *(const float4*)(xp + 4);

    #pragma unroll
    for (int h = 0; h < 2; ++h) {
        float kd[4], vd[4];
        #pragma unroll
        for (int d = 0; d < 4; ++d) {
            const int r = (h * 4 + d) * 8;
            float sk = 0.f, sv = 0.f;
            #pragma unroll
            for (int e = 0; e < 8; ++e) {          // identical chain to old
                sk += xv[e] * wrow[r + e];         // LDS staging -> same bits
                sv += xv[e] * wrow[64 + r + e];
            }
            kd[d] = sk; vd[d] = sv;
        }
        const size_t o = ((size_t)(b * 2 + h) * SS + s) * 2;
        kvws[o]     = make_float4(kd[0], kd[1], kd[2], kd[3]);
        kvws[o + 1] = make_float4(vd[0], vd[1], vd[2], vd[3]);
    }
}

// grid 2048: bid = b<<8 | h<<7 | rt<<3 | jw.  256 threads = 4 waves.
// Block: rows rt*128..+127 (2 per lane), j-window jw*256..+255 (64 per wave).
// K/V come in via s_load (AS4, uniform addr) -- no LDS/VMEM in main loop.
extern "C" __global__ __launch_bounds__(256, 8)
void qa_attn15(const float* __restrict__ x, const float* __restrict__ Wq,
               const float4* __restrict__ kvws,
               float* __restrict__ wsD, float4* __restrict__ wsA) {
    __shared__ float wrow[32];                    // wq' (scaled)
    __shared__ float rden[3 * 128];               // waves 1..3 partials
    __shared__ __align__(16) float4 racc[3 * 128];// 6 KB

    const int bid = blockIdx.x;
    const int jw = bid & 7, rt = (bid >> 3) & 15, h = (bid >> 7) & 1, b = bid >> 8;
    const int tid = threadIdx.x, lane = tid & 63;
    const int w = __builtin_amdgcn_readfirstlane(tid >> 6);  // provably uniform

    if (tid < 32) {
        const int d = tid >> 3, e = tid & 7;
        wrow[tid] = Wq[(h * 4 + d) * EE + e] * 0.72134752044f;  // 0.5*log2(e)
    }
    __syncthreads();   // wrow ready

    // ---- q' (log2-scaled) for this lane's 2 rows ----
    float q[2][4];
    const int row0 = rt * 128 + lane;
    #pragma unroll
    for (int m = 0; m < 2; ++m) {
        const float* xp = x + ((size_t)(b * SS + row0 + m * 64)) * EE;
        float xv[8];
        *(float4*)&xv[0] = *(const float4*)xp;
        *(float4*)&xv[4] = *(const float4*)(xp + 4);
        #pragma unroll
        for (int d = 0; d < 4; ++d) {
            float s = 0.f;
            #pragma unroll
            for (int e = 0; e < 8; ++e) s += xv[e] * wrow[d * 8 + e];
            q[m][d] = s;
        }
    }

    // ---- 64-j slice for this wave, m-packed fp32, K/V via s_load ----
    v2f qp[4];
    #pragma unroll
    for (int d = 0; d < 4; ++d) qp[d] = (v2f){q[0][d], q[1][d]};
    v2f denp = (v2f){0.f, 0.f};
    v2f accp[4];
    #pragma unroll
    for (int c = 0; c < 4; ++c) accp[c] = (v2f){0.f, 0.f};

    const size_t base = ((size_t)((b * 2 + h)) * SS + jw * 256 + w * 64) * 8;
    const c4f* kvp = (const c4f*)(unsigned long long)((const float*)kvws + base);

    #pragma unroll 4
    for (int jl = 0; jl < 64; ++jl) {
        const float k0 = kvp[jl * 8 + 0], k1 = kvp[jl * 8 + 1];
        const float k2 = kvp[jl * 8 + 2], k3 = kvp[jl * 8 + 3];
        const float v0 = kvp[jl * 8 + 4], v1 = kvp[jl * 8 + 5];
        const float v2 = kvp[jl * 8 + 6], v3 = kvp[jl * 8 + 7];
        v2f s = qp[0] * (v2f){k0, k0};
        s = __builtin_elementwise_fma(qp[1], (v2f){k1, k1}, s);
        s = __builtin_elementwise_fma(qp[2], (v2f){k2, k2}, s);
        s = __builtin_elementwise_fma(qp[3], (v2f){k3, k3}, s);
        v2f e;
        e.x = __builtin_amdgcn_exp2f(s.x);
        e.y = __builtin_amdgcn_exp2f(s.y);
        denp += e;
        accp[0] = __builtin_elementwise_fma(e, (v2f){v0, v0}, accp[0]);
        accp[1] = __builtin_elementwise_fma(e, (v2f){v1, v1}, accp[1]);
        accp[2] = __builtin_elementwise_fma(e, (v2f){v2, v2}, accp[2]);
        accp[3] = __builtin_elementwise_fma(e, (v2f){v3, v3}, accp[3]);
    }

    float den[2] = {denp.x, denp.y};
    float acc[2][4];
    #pragma unroll
    for (int c = 0; c < 4; ++c) { acc[0][c] = accp[c].x; acc[1][c] = accp[c].y; }

    // ---- single-stage reduce: waves 1..3 park, wave 0 merges + writes ----
    if (w > 0) {
        #pragma unroll
        for (int m = 0; m < 2; ++m) {
            rden[(w - 1) * 128 + lane + m * 64] = den[m];
            racc[(w - 1) * 128 + lane + m * 64] =
                make_float4(acc[m][0], acc[m][1], acc[m][2], acc[m][3]);
        }
    }
    __syncthreads();
    if (w == 0) {
        #pragma unroll
        for (int m = 0; m < 2; ++m) {
            const int r = lane + m * 64;
            float d = den[m] + rden[r] + rden[128 + r] + rden[256 + r];
            float4 a1 = racc[r], a2 = racc[128 + r], a3 = racc[256 + r];
            float4 a = make_float4(acc[m][0] + a1.x + a2.x + a3.x,
                                   acc[m][1] + a1.y + a2.y + a3.y,
                                   acc[m][2] + a1.z + a2.z + a3.z,
                                   acc[m][3] + a1.w + a2.w + a3.w);
            const size_t idx = ((size_t)((b * 2 + h) * 8 + jw)) * SS + row0 + m * 64;
            wsD[idx] = d;
            wsA[idx] = a;
        }
    }
}

// ---- merge + quantum: 2 threads/token (one per head), shfl_xor exchange.
// UNCHANGED from R9/R14 (bit-identical).
extern "C" __global__ __launch_bounds__(256)
void qa_merge15(const float* __restrict__ wsD, const float4* __restrict__ wsA,
                const float* __restrict__ Wo, float* __restrict__ out) {
    __shared__ float wo[64];
    const int tid = threadIdx.x;
    if (tid < 64) wo[tid] = Wo[tid];
    __syncthreads();

    const int gt = blockIdx.x * 256 + tid;   // 0..32767
    const int g = gt >> 1, h = gt & 1;       // token, head
    const int b = g >> 11, s = g & 2047;

    float den = 0.f, a0 = 0.f, a1 = 0.f, a2 = 0.f, a3 = 0.f;
    #pragma unroll
    for (int sl = 0; sl < 8; ++sl) {
        const size_t idx = ((size_t)((b * 2 + h) * 8 + sl)) * SS + s;
        den += wsD[idx];
        const float4 p = wsA[idx];
        a0 += p.x; a1 += p.y; a2 += p.z; a3 += p.w;
    }
    const float inv = 1.f / den;
    float own[4] = {a0 * inv, a1 * inv, a2 * inv, a3 * inv};
    float oth[4];
    #pragma unroll
    for (int c = 0; c < 4; ++c) oth[c] = __shfl_xor(own[c], 1);

    float tok[8];
    #pragma unroll
    for (int c = 0; c < 4; ++c) {
        tok[c]     = h ? oth[c] : own[c];
        tok[4 + c] = h ? own[c] : oth[c];
    }

    float cc[8];
    #pragma unroll
    for (int ww = 0; ww < 8; ++ww) cc[ww] = __cosf(tok[ww] + tok[ww & 3]);

    float z[8];
    float p = 1.f;
    #pragma unroll
    for (int qq = 1; qq < 8; ++qq) { p *= cc[qq]; z[qq] = p; }
    z[0] = p;                       // c1..c7
    #pragma unroll
    for (int qq = 1; qq < 8; ++qq) z[qq] *= cc[0];   // c0..cq

    // this thread writes outputs f = h*4 .. h*4+3
    float y[4];
    #pragma unroll
    for (int f = 0; f < 4; ++f) {
        float sum = 0.f;
        #pragma unroll
        for (int qq = 0; qq < 8; ++qq) sum += z[qq] * wo[(h * 4 + f) * 8 + qq];
        y[f] = sum;
    }
    float4* op = (float4*)(out + (size_t)g * 8) + h;
    *op = make_float4(y[0], y[1], y[2], y[3]);
}

extern "C" void kernel_launch(void* const* d_in, const int* in_sizes, int n_in,
                              void* d_out, int out_size, void* d_ws, size_t ws_size,
                              hipStream_t stream) {
    const float* x  = (const float*)d_in[0];
    const float* Wq = (const float*)d_in[1];
    const float* Wk = (const float*)d_in[2];
    const float* Wv = (const float*)d_in[3];
    const float* Wo = (const float*)d_in[4];
    float* out = (float*)d_out;

    // ws layout: [kvws 1MB][wsD 1MB][wsA 4MB]
    float4* kvws = (float4*)d_ws;
    float*  wsD  = (float*)((char*)d_ws + (1u << 20));
    float4* wsA  = (float4*)((char*)d_ws + (2u << 20));

    qa_prep15<<<dim3(128), dim3(128), 0, stream>>>(x, Wk, Wv, kvws);
    qa_attn15<<<dim3(2048), dim3(256), 0, stream>>>(x, Wq, kvws, wsD, wsA);
    qa_merge15<<<dim3(128), dim3(256), 0, stream>>>(wsD, wsA, Wo, out);
}

// Round 11
// 84.350 us; speedup vs baseline: 1.0003x; 1.0003x over previous
//
#include <hip/hip_runtime.h>

// QuantumAttention: B=8, S=2048, E=8, H=2, D=4, NQ=8
//
// Ledger (rocprof-anchored): total = fill 40.5 + 17.5 fixed harness/graph
// + attn + merge 2.6. Best = R14 83.8 (pk-packed fp32, M=2, LDS broadcast).
// Model correction (R5/R13 M-null + R14 +3 + R15 +2 => broadcast ds_read
// is ~2-4cyc, NOT 12 -- wave-uniform reads return 16B once): attn ~23 =
// FP32 exec ~8 + trans ~3.4 + staging/reduce ~4 + EXPOSED LGKMCNT/latency
// ~6-8. R16 attacks the latency term: explicit 4-j read batching (8 x
// ds_read_b128 issued per group, then 4 j of pk-math) -> compiler emits
// counted lgkmcnt waits, group t+1 reads overlap group t math. VGPR ~58
// (under the (256,8) 64-cap, no spill). Accumulation order per row
// unchanged -> bit-identical. All else byte-identical to R14.
// Dead mechanisms: readlane (63us), DPP rotate (39), vector-uniform global
// (36), cross-block fusion (89), M=4 geometries (26-34), SMEM+prep (84.4).
//
// Quantum circuit closed-form: c_w = cos(tok[w]+tok[w%4]);
// z[0]=c1..c7, z[q>=1]=c0..cq. Softmax one-pass (scores bounded, fp32 safe);
// 0.5*log2(e) folded into Wq so inner exp is bare v_exp_f32 (exp2).

#define SS 2048
#define EE 8

typedef float v2f __attribute__((ext_vector_type(2)));

// grid 2048: bid = b<<8 | h<<7 | rt<<3 | jw.  256 threads = 4 waves.
// Block: rows rt*128..+127 (2 per lane), j-window jw*256..+255 (64 per wave).
extern "C" __global__ __launch_bounds__(256, 8)
void qa_attn16(const float* __restrict__ x, const float* __restrict__ Wq,
               const float* __restrict__ Wk, const float* __restrict__ Wv,
               float* __restrict__ wsD, float4* __restrict__ wsA) {
    __shared__ float wrow[96];                    // wq'(scaled), wk, wv
    __shared__ __align__(16) float4 kv4[512];     // 256 j x {K4,V4} = 8 KB
    __shared__ float rden[3 * 128];               // waves 1..3 partials
    __shared__ __align__(16) float4 racc[3 * 128];// 6 KB

    const int bid = blockIdx.x;
    const int jw = bid & 7, rt = (bid >> 3) & 15, h = (bid >> 7) & 1, b = bid >> 8;
    const int tid = threadIdx.x, lane = tid & 63, w = tid >> 6;

    if (tid < 96) {
        const int grp = tid >> 5, d = (tid >> 3) & 3, e = tid & 7;
        const float* W = (grp == 0) ? Wq : (grp == 1 ? Wk : Wv);
        float val = W[(h * 4 + d) * EE + e];
        if (grp == 0) val *= 0.72134752044f;   // 0.5 * log2(e)
        wrow[tid] = val;
    }
    __syncthreads();   // wrow ready

    // ---- stage K,V for the 256-j window (one j per thread) ----
    {
        const int j = jw * 256 + tid;
        const float* xp = x + ((size_t)(b * SS + j)) * EE;
        float xv[8];
        *(float4*)&xv[0] = *(const float4*)xp;
        *(float4*)&xv[4] = *(const float4*)(xp + 4);
        float kk[4], vv[4];
        #pragma unroll
        for (int d = 0; d < 4; ++d) {
            float sk = 0.f, sv = 0.f;
            #pragma unroll
            for (int e = 0; e < 8; ++e) {
                sk += xv[e] * wrow[32 + d * 8 + e];
                sv += xv[e] * wrow[64 + d * 8 + e];
            }
            kk[d] = sk; vv[d] = sv;
        }
        kv4[tid * 2]     = make_float4(kk[0], kk[1], kk[2], kk[3]);
        kv4[tid * 2 + 1] = make_float4(vv[0], vv[1], vv[2], vv[3]);
    }

    // ---- q' (log2-scaled) for this lane's 2 rows ----
    float q[2][4];
    const int row0 = rt * 128 + lane;
    #pragma unroll
    for (int m = 0; m < 2; ++m) {
        const float* xp = x + ((size_t)(b * SS + row0 + m * 64)) * EE;
        float xv[8];
        *(float4*)&xv[0] = *(const float4*)xp;
        *(float4*)&xv[4] = *(const float4*)(xp + 4);
        #pragma unroll
        for (int d = 0; d < 4; ++d) {
            float s = 0.f;
            #pragma unroll
            for (int e = 0; e < 8; ++e) s += xv[e] * wrow[d * 8 + e];
            q[m][d] = s;
        }
    }
    __syncthreads();   // kv4 ready

    // ---- 64-j slice for this wave, 2 rows per lane, m-packed fp32.
    //      4-j read batching: 8 ds_read_b128 issued, then 4 j of math. ----
    v2f qp[4];
    #pragma unroll
    for (int d = 0; d < 4; ++d) qp[d] = (v2f){q[0][d], q[1][d]};
    v2f denp = (v2f){0.f, 0.f};
    v2f accp[4];
    #pragma unroll
    for (int c = 0; c < 4; ++c) accp[c] = (v2f){0.f, 0.f};

    const float4* kvp = &kv4[w * 128];
    #pragma unroll 2
    for (int jt = 0; jt < 16; ++jt) {
        float4 kb[4], vb[4];
        #pragma unroll
        for (int u = 0; u < 4; ++u) {
            kb[u] = kvp[(jt * 4 + u) * 2];       // wave-broadcast reads,
            vb[u] = kvp[(jt * 4 + u) * 2 + 1];   // batched: 8 in flight
        }
        #pragma unroll
        for (int u = 0; u < 4; ++u) {
            const float4 kk = kb[u], vv = vb[u];
            v2f s = qp[0] * (v2f){kk.x, kk.x};
            s = __builtin_elementwise_fma(qp[1], (v2f){kk.y, kk.y}, s);
            s = __builtin_elementwise_fma(qp[2], (v2f){kk.z, kk.z}, s);
            s = __builtin_elementwise_fma(qp[3], (v2f){kk.w, kk.w}, s);
            v2f e;
            e.x = __builtin_amdgcn_exp2f(s.x);
            e.y = __builtin_amdgcn_exp2f(s.y);
            denp += e;                           // v_pk_add_f32
            accp[0] = __builtin_elementwise_fma(e, (v2f){vv.x, vv.x}, accp[0]);
            accp[1] = __builtin_elementwise_fma(e, (v2f){vv.y, vv.y}, accp[1]);
            accp[2] = __builtin_elementwise_fma(e, (v2f){vv.z, vv.z}, accp[2]);
            accp[3] = __builtin_elementwise_fma(e, (v2f){vv.w, vv.w}, accp[3]);
        }
    }

    float den[2] = {denp.x, denp.y};
    float acc[2][4];
    #pragma unroll
    for (int c = 0; c < 4; ++c) { acc[0][c] = accp[c].x; acc[1][c] = accp[c].y; }

    // ---- single-stage reduce: waves 1..3 park, wave 0 merges + writes ----
    if (w > 0) {
        #pragma unroll
        for (int m = 0; m < 2; ++m) {
            rden[(w - 1) * 128 + lane + m * 64] = den[m];
            racc[(w - 1) * 128 + lane + m * 64] =
                make_float4(acc[m][0], acc[m][1], acc[m][2], acc[m][3]);
        }
    }
    __syncthreads();
    if (w == 0) {
        #pragma unroll
        for (int m = 0; m < 2; ++m) {
            const int r = lane + m * 64;
            float d = den[m] + rden[r] + rden[128 + r] + rden[256 + r];
            float4 a1 = racc[r], a2 = racc[128 + r], a3 = racc[256 + r];
            float4 a = make_float4(acc[m][0] + a1.x + a2.x + a3.x,
                                   acc[m][1] + a1.y + a2.y + a3.y,
                                   acc[m][2] + a1.z + a2.z + a3.z,
                                   acc[m][3] + a1.w + a2.w + a3.w);
            const size_t idx = ((size_t)((b * 2 + h) * 8 + jw)) * SS + row0 + m * 64;
            wsD[idx] = d;
            wsA[idx] = a;
        }
    }
}

// ---- merge + quantum: 2 threads/token (one per head), shfl_xor exchange.
// UNCHANGED from R9/R14 (bit-identical).
extern "C" __global__ __launch_bounds__(256)
void qa_merge16(const float* __restrict__ wsD, const float4* __restrict__ wsA,
                const float* __restrict__ Wo, float* __restrict__ out) {
    __shared__ float wo[64];
    const int tid = threadIdx.x;
    if (tid < 64) wo[tid] = Wo[tid];
    __syncthreads();

    const int gt = blockIdx.x * 256 + tid;   // 0..32767
    const int g = gt >> 1, h = gt & 1;       // token, head
    const int b = g >> 11, s = g & 2047;

    float den = 0.f, a0 = 0.f, a1 = 0.f, a2 = 0.f, a3 = 0.f;
    #pragma unroll
    for (int sl = 0; sl < 8; ++sl) {
        const size_t idx = ((size_t)((b * 2 + h) * 8 + sl)) * SS + s;
        den += wsD[idx];
        const float4 p = wsA[idx];
        a0 += p.x; a1 += p.y; a2 += p.z; a3 += p.w;
    }
    const float inv = 1.f / den;
    float own[4] = {a0 * inv, a1 * inv, a2 * inv, a3 * inv};
    float oth[4];
    #pragma unroll
    for (int c = 0; c < 4; ++c) oth[c] = __shfl_xor(own[c], 1);

    float tok[8];
    #pragma unroll
    for (int c = 0; c < 4; ++c) {
        tok[c]     = h ? oth[c] : own[c];
        tok[4 + c] = h ? own[c] : oth[c];
    }

    float cc[8];
    #pragma unroll
    for (int ww = 0; ww < 8; ++ww) cc[ww] = __cosf(tok[ww] + tok[ww & 3]);

    float z[8];
    float p = 1.f;
    #pragma unroll
    for (int qq = 1; qq < 8; ++qq) { p *= cc[qq]; z[qq] = p; }
    z[0] = p;                       // c1..c7
    #pragma unroll
    for (int qq = 1; qq < 8; ++qq) z[qq] *= cc[0];   // c0..cq

    // this thread writes outputs f = h*4 .. h*4+3
    float y[4];
    #pragma unroll
    for (int f = 0; f < 4; ++f) {
        float sum = 0.f;
        #pragma unroll
        for (int qq = 0; qq < 8; ++qq) sum += z[qq] * wo[(h * 4 + f) * 8 + qq];
        y[f] = sum;
    }
    float4* op = (float4*)(out + (size_t)g * 8) + h;
    *op = make_float4(y[0], y[1], y[2], y[3]);
}

extern "C" void kernel_launch(void* const* d_in, const int* in_sizes, int n_in,
                              void* d_out, int out_size, void* d_ws, size_t ws_size,
                              hipStream_t stream) {
    const float* x  = (const float*)d_in[0];
    const float* Wq = (const float*)d_in[1];
    const float* Wk = (const float*)d_in[2];
    const float* Wv = (const float*)d_in[3];
    const float* Wo = (const float*)d_in[4];
    float* out = (float*)d_out;

    float*  wsD = (float*)d_ws;                          // 16*8*2048 floats = 1 MB
    float4* wsA = (float4*)((char*)d_ws + (16 * 8 * 2048) * sizeof(float)); // 4 MB

    qa_attn16<<<dim3(2048), dim3(256), 0, stream>>>(x, Wq, Wk, Wv, wsD, wsA);
    qa_merge16<<<dim3(128), dim3(256), 0, stream>>>(wsD, wsA, Wo, out);
}

// Round 12
// 83.617 us; speedup vs baseline: 1.0091x; 1.0088x over previous
//
#include <hip/hip_runtime.h>

// QuantumAttention: B=8, S=2048, E=8, H=2, D=4, NQ=8
//
// Ledger (rocprof-anchored): total = fill 40.5 + 17.5 fixed harness/graph
// + attn + merge 2.6. Best = R14 83.8 (pk-packed fp32, M=2, LDS broadcast).
// attn ~23us vs ~7us issue floor; R16 (batched LDS reads) null -> LDS
// latency not the residual. Remaining suspect: prologue -- wrow-in-LDS
// forces W-value hoisting against the 64-VGPR cap + per-fma LDS reads,
// and 2 lockstep barriers + post-fill L2-writeback storm (attn7 PMC:
// 33MB fetch / 79MB write = poison evictions) stall all waves together.
// R17: W via SCALAR pipe (AS4 s_load -- mechanism validated in R15):
// deletes wrow LDS + 1 barrier + ~100 prologue ops/thread, frees ~24 VGPR.
// Staging fma = v_fma(vgpr, sgpr, vgpr), K/V chain bit-identical; q scale
// applied as pk-mul post-dot (last-ulp change, tolerance-proven in R8).
// Main loop / reduce / merge byte-identical to R14.
// Dead: readlane(63) DPP(39) vec-uniform-global(36) fusion(89) M=4(26-34)
// SMEM-KV+prep(84.4) read-batching(null).
//
// Quantum circuit closed-form: c_w = cos(tok[w]+tok[w%4]);
// z[0]=c1..c7, z[q>=1]=c0..cq. Softmax one-pass (scores bounded, fp32 safe);
// log2(e)/2 applied to q after the dot so inner exp is bare v_exp_f32.

#define SS 2048
#define EE 8

typedef float v2f __attribute__((ext_vector_type(2)));
typedef __attribute__((address_space(4))) const float c4f;   // s_load path

// grid 2048: bid = b<<8 | h<<7 | rt<<3 | jw.  256 threads = 4 waves.
// Block: rows rt*128..+127 (2 per lane), j-window jw*256..+255 (64 per wave).
extern "C" __global__ __launch_bounds__(256, 8)
void qa_attn17(const float* __restrict__ x, const float* __restrict__ Wq,
               const float* __restrict__ Wk, const float* __restrict__ Wv,
               float* __restrict__ wsD, float4* __restrict__ wsA) {
    __shared__ __align__(16) float4 kv4[512];     // 256 j x {K4,V4} = 8 KB
    __shared__ float rden[3 * 128];               // waves 1..3 partials
    __shared__ __align__(16) float4 racc[3 * 128];// 6 KB

    const int bid = blockIdx.x;
    const int jw = bid & 7, rt = (bid >> 3) & 15, h = (bid >> 7) & 1, b = bid >> 8;
    const int tid = threadIdx.x, lane = tid & 63, w = tid >> 6;

    // ---- W rows for this head via the scalar pipe (s_load, no LDS/barrier)
    const c4f* wq = (const c4f*)(unsigned long long)(Wq + h * 32);
    const c4f* wk = (const c4f*)(unsigned long long)(Wk + h * 32);
    const c4f* wv = (const c4f*)(unsigned long long)(Wv + h * 32);

    // ---- stage K,V for the 256-j window (one j per thread) ----
    {
        const int j = jw * 256 + tid;
        const float* xp = x + ((size_t)(b * SS + j)) * EE;
        float xv[8];
        *(float4*)&xv[0] = *(const float4*)xp;
        *(float4*)&xv[4] = *(const float4*)(xp + 4);
        float kk[4], vv[4];
        #pragma unroll
        for (int d = 0; d < 4; ++d) {
            float sk = 0.f, sv = 0.f;
            #pragma unroll
            for (int e = 0; e < 8; ++e) {
                sk += xv[e] * wk[d * 8 + e];   // v_fma(vgpr, sgpr, vgpr)
                sv += xv[e] * wv[d * 8 + e];
            }
            kk[d] = sk; vv[d] = sv;
        }
        kv4[tid * 2]     = make_float4(kk[0], kk[1], kk[2], kk[3]);
        kv4[tid * 2 + 1] = make_float4(vv[0], vv[1], vv[2], vv[3]);
    }

    // ---- q (then log2-scale as pk-mul) for this lane's 2 rows ----
    float q[2][4];
    const int row0 = rt * 128 + lane;
    #pragma unroll
    for (int m = 0; m < 2; ++m) {
        const float* xp = x + ((size_t)(b * SS + row0 + m * 64)) * EE;
        float xv[8];
        *(float4*)&xv[0] = *(const float4*)xp;
        *(float4*)&xv[4] = *(const float4*)(xp + 4);
        #pragma unroll
        for (int d = 0; d < 4; ++d) {
            float s = 0.f;
            #pragma unroll
            for (int e = 0; e < 8; ++e) s += xv[e] * wq[d * 8 + e];
            q[m][d] = s;
        }
    }
    __syncthreads();   // kv4 ready (single barrier)

    // ---- 64-j slice for this wave, 2 rows per lane, m-packed fp32 ----
    const v2f lg2e = (v2f){0.72134752044f, 0.72134752044f};  // 0.5*log2(e)
    v2f qp[4];
    #pragma unroll
    for (int d = 0; d < 4; ++d) qp[d] = (v2f){q[0][d], q[1][d]} * lg2e;
    v2f denp = (v2f){0.f, 0.f};
    v2f accp[4];
    #pragma unroll
    for (int c = 0; c < 4; ++c) accp[c] = (v2f){0.f, 0.f};

    const float4* kvp = &kv4[w * 128];
    #pragma unroll 2
    for (int jl = 0; jl < 64; ++jl) {
        const float4 kk = kvp[jl * 2];      // wave-broadcast
        const float4 vv = kvp[jl * 2 + 1];
        v2f s = qp[0] * (v2f){kk.x, kk.x};
        s = __builtin_elementwise_fma(qp[1], (v2f){kk.y, kk.y}, s);
        s = __builtin_elementwise_fma(qp[2], (v2f){kk.z, kk.z}, s);
        s = __builtin_elementwise_fma(qp[3], (v2f){kk.w, kk.w}, s);
        v2f e;
        e.x = __builtin_amdgcn_exp2f(s.x);
        e.y = __builtin_amdgcn_exp2f(s.y);
        denp += e;                           // v_pk_add_f32
        accp[0] = __builtin_elementwise_fma(e, (v2f){vv.x, vv.x}, accp[0]);
        accp[1] = __builtin_elementwise_fma(e, (v2f){vv.y, vv.y}, accp[1]);
        accp[2] = __builtin_elementwise_fma(e, (v2f){vv.z, vv.z}, accp[2]);
        accp[3] = __builtin_elementwise_fma(e, (v2f){vv.w, vv.w}, accp[3]);
    }

    float den[2] = {denp.x, denp.y};
    float acc[2][4];
    #pragma unroll
    for (int c = 0; c < 4; ++c) { acc[0][c] = accp[c].x; acc[1][c] = accp[c].y; }

    // ---- single-stage reduce: waves 1..3 park, wave 0 merges + writes ----
    if (w > 0) {
        #pragma unroll
        for (int m = 0; m < 2; ++m) {
            rden[(w - 1) * 128 + lane + m * 64] = den[m];
            racc[(w - 1) * 128 + lane + m * 64] =
                make_float4(acc[m][0], acc[m][1], acc[m][2], acc[m][3]);
        }
    }
    __syncthreads();
    if (w == 0) {
        #pragma unroll
        for (int m = 0; m < 2; ++m) {
            const int r = lane + m * 64;
            float d = den[m] + rden[r] + rden[128 + r] + rden[256 + r];
            float4 a1 = racc[r], a2 = racc[128 + r], a3 = racc[256 + r];
            float4 a = make_float4(acc[m][0] + a1.x + a2.x + a3.x,
                                   acc[m][1] + a1.y + a2.y + a3.y,
                                   acc[m][2] + a1.z + a2.z + a3.z,
                                   acc[m][3] + a1.w + a2.w + a3.w);
            const size_t idx = ((size_t)((b * 2 + h) * 8 + jw)) * SS + row0 + m * 64;
            wsD[idx] = d;
            wsA[idx] = a;
        }
    }
}

// ---- merge + quantum: 2 threads/token (one per head), shfl_xor exchange.
// UNCHANGED from R9/R14 (bit-identical).
extern "C" __global__ __launch_bounds__(256)
void qa_merge17(const float* __restrict__ wsD, const float4* __restrict__ wsA,
                const float* __restrict__ Wo, float* __restrict__ out) {
    __shared__ float wo[64];
    const int tid = threadIdx.x;
    if (tid < 64) wo[tid] = Wo[tid];
    __syncthreads();

    const int gt = blockIdx.x * 256 + tid;   // 0..32767
    const int g = gt >> 1, h = gt & 1;       // token, head
    const int b = g >> 11, s = g & 2047;

    float den = 0.f, a0 = 0.f, a1 = 0.f, a2 = 0.f, a3 = 0.f;
    #pragma unroll
    for (int sl = 0; sl < 8; ++sl) {
        const size_t idx = ((size_t)((b * 2 + h) * 8 + sl)) * SS + s;
        den += wsD[idx];
        const float4 p = wsA[idx];
        a0 += p.x; a1 += p.y; a2 += p.z; a3 += p.w;
    }
    const float inv = 1.f / den;
    float own[4] = {a0 * inv, a1 * inv, a2 * inv, a3 * inv};
    float oth[4];
    #pragma unroll
    for (int c = 0; c < 4; ++c) oth[c] = __shfl_xor(own[c], 1);

    float tok[8];
    #pragma unroll
    for (int c = 0; c < 4; ++c) {
        tok[c]     = h ? oth[c] : own[c];
        tok[4 + c] = h ? own[c] : oth[c];
    }

    float cc[8];
    #pragma unroll
    for (int ww = 0; ww < 8; ++ww) cc[ww] = __cosf(tok[ww] + tok[ww & 3]);

    float z[8];
    float p = 1.f;
    #pragma unroll
    for (int qq = 1; qq < 8; ++qq) { p *= cc[qq]; z[qq] = p; }
    z[0] = p;                       // c1..c7
    #pragma unroll
    for (int qq = 1; qq < 8; ++qq) z[qq] *= cc[0];   // c0..cq

    // this thread writes outputs f = h*4 .. h*4+3
    float y[4];
    #pragma unroll
    for (int f = 0; f < 4; ++f) {
        float sum = 0.f;
        #pragma unroll
        for (int qq = 0; qq < 8; ++qq) sum += z[qq] * wo[(h * 4 + f) * 8 + qq];
        y[f] = sum;
    }
    float4* op = (float4*)(out + (size_t)g * 8) + h;
    *op = make_float4(y[0], y[1], y[2], y[3]);
}

extern "C" void kernel_launch(void* const* d_in, const int* in_sizes, int n_in,
                              void* d_out, int out_size, void* d_ws, size_t ws_size,
                              hipStream_t stream) {
    const float* x  = (const float*)d_in[0];
    const float* Wq = (const float*)d_in[1];
    const float* Wk = (const float*)d_in[2];
    const float* Wv = (const float*)d_in[3];
    const float* Wo = (const float*)d_in[4];
    float* out = (float*)d_out;

    float*  wsD = (float*)d_ws;                          // 16*8*2048 floats = 1 MB
    float4* wsA = (float4*)((char*)d_ws + (16 * 8 * 2048) * sizeof(float)); // 4 MB

    qa_attn17<<<dim3(2048), dim3(256), 0, stream>>>(x, Wq, Wk, Wv, wsD, wsA);
    qa_merge17<<<dim3(128), dim3(256), 0, stream>>>(wsD, wsA, Wo, out);
}